// Round 18
// baseline (172.089 us; speedup 1.0000x reference)
//
#include <hip/hip_runtime.h>
#include <hip/hip_bf16.h>
#include <hip/hip_fp16.h>
#include <math.h>

#define D   256
#define SE  512
#define SC  512
#define CKS 8
#define NC  64   // SC / CKS
#define KC  3

typedef __attribute__((ext_vector_type(8))) short short8_t;
typedef __attribute__((ext_vector_type(4))) float f32x4;
typedef _Float16 h2_t __attribute__((ext_vector_type(2)));
typedef _Float16 h8_t __attribute__((ext_vector_type(8)));

__device__ __forceinline__ float sigmoidf_(float x) { return 1.f / (1.f + __expf(-x)); }
__device__ __forceinline__ short bf16s(float f) {
    union { __hip_bfloat16 h; short s; } u; u.h = __float2bfloat16(f); return u.s;
}
__device__ __forceinline__ float bflo(unsigned int u) {
    union { unsigned int u; float f; } v; v.u = u << 16; return v.f;
}
__device__ __forceinline__ short h16s(float f) {
    union { _Float16 h; short s; } u; u.h = (_Float16)f; return u.s;
}
__device__ __forceinline__ float h16f(short s) {
    union { short s; _Float16 h; } u; u.s = s; return (float)u.h;
}
__device__ __forceinline__ h2_t h2u(unsigned int u) {
    union { unsigned int u; h2_t h; } v; v.u = u; return v.h;
}
__device__ __forceinline__ unsigned int u2h(h2_t h) {
    union { unsigned int u; h2_t h; } v; v.h = h; return v.u;
}
__device__ __forceinline__ float hdot2(h2_t a, h2_t b, float c) {
#if __has_builtin(__builtin_amdgcn_fdot2)
    return __builtin_amdgcn_fdot2(a, b, c, false);
#else
    h2_t p = a * b;
    return c + (float)p[0] + (float)p[1];
#endif
}
#define GLOAD_LDS16(g, l) \
    __builtin_amdgcn_global_load_lds((const __attribute__((address_space(1))) void*)(g), \
                                     (__attribute__((address_space(3))) void*)(l), 16, 0, 0)

// ============ prep: all weight conversions ============
__global__ __launch_bounds__(256) void prep_all_kernel(
    const float* __restrict__ W3, const float* __restrict__ Wih,
    const float* __restrict__ Whh, const float* __restrict__ WW,
    const float* __restrict__ repW, const float* __restrict__ clsW,
    short* __restrict__ Bprep, uint2* __restrict__ Wih16, uint2* __restrict__ Whh16,
    float4* __restrict__ WWq, float4* __restrict__ W3q,
    float4* __restrict__ repWq, unsigned int* __restrict__ clsP)
{
    const int b = blockIdx.x, t = threadIdx.x;
    if (b < 32) {
        const int idx = b * 256 + t;
        const int p = idx >> 11, k = (idx >> 3) & 255, G = idx & 7;
        const int dbase = p * 64 + ((G ^ (k & 7)) << 3);
        #pragma unroll
        for (int e = 0; e < 8; ++e)
            Bprep[idx * 8 + e] = h16s(W3[(size_t)(513 + dbase + e) * D + k]);   // fp16
    } else if (b < 416) {
        const bool ih = (b < 224);
        const int tid = (b - (ih ? 32 : 224)) * 256 + t;
        const float* W = ih ? Wih : Whh;
        const int base = (tid / 768) * 4 * 768 + (tid % 768);
        float f0 = W[base], f1 = W[base + 768], f2 = W[base + 1536], f3 = W[base + 2304];
        __half2 plo = __halves2half2(__float2half_rn(f0), __float2half_rn(f1));
        __half2 phi = __halves2half2(__float2half_rn(f2), __float2half_rn(f3));
        uint2 o; o.x = *(unsigned int*)&plo; o.y = *(unsigned int*)&phi;
        (ih ? Wih16 : Whh16)[tid] = o;
    } else if (b < 672) {
        const bool ww = (b < 544);
        const int tid = (b - (ww ? 416 : 544)) * 256 + t;
        const int h = tid >> 14, rem = tid & 16383, d4 = rem >> 8, k = rem & 255;
        const float* src = (ww ? WW : W3) + (size_t)(h * 256 + 4 * d4) * D + k;
        (ww ? WWq : W3q)[tid] = make_float4(src[0], src[256], src[512], src[768]);
    } else if (b < 736) {
        const int tid = (b - 672) * 256 + t;
        const int d4 = tid >> 8, k = tid & 255;
        const float* src = repW + (size_t)(4 * d4) * D + k;
        repWq[tid] = make_float4(src[0], src[256], src[512], src[768]);
    } else {
        unsigned int c0 = (unsigned int)(unsigned short)bf16s(clsW[t * 2]);
        unsigned int c1 = (unsigned int)(unsigned short)bf16s(clsW[t * 2 + 1]);
        clsP[t] = c0 | (c1 << 16);
    }
}

// ============ rep: 4 rows/block (f32 + f16 outputs) + fused sq-sums ============
__global__ __launch_bounds__(256) void rep4_kernel(
    const float* __restrict__ te, const float* __restrict__ tc,
    const float4* __restrict__ repWq, const float* __restrict__ b,
    float* __restrict__ emo, float* __restrict__ cau,
    short* __restrict__ emoH, short* __restrict__ cauH,
    float* __restrict__ se2, float* __restrict__ sc2)
{
    const int r0 = blockIdx.x * 4, t = threadIdx.x;
    const float* X = (r0 < SE) ? (te + (size_t)r0 * D) : (tc + (size_t)(r0 - SE) * D);
    __shared__ __align__(16) float xs[4][D];
    #pragma unroll
    for (int r = 0; r < 4; ++r) xs[r][t] = X[r * D + t];
    __syncthreads();
    float acc0 = 0.f, acc1 = 0.f, acc2 = 0.f, acc3 = 0.f;
    #pragma unroll 8
    for (int q = 0; q < 64; ++q) {
        float4 w = repWq[q * 256 + t];
        float4 x0 = *(const float4*)&xs[0][q * 4];
        float4 x1 = *(const float4*)&xs[1][q * 4];
        float4 x2 = *(const float4*)&xs[2][q * 4];
        float4 x3 = *(const float4*)&xs[3][q * 4];
        acc0 = fmaf(x0.x, w.x, acc0); acc0 = fmaf(x0.y, w.y, acc0); acc0 = fmaf(x0.z, w.z, acc0); acc0 = fmaf(x0.w, w.w, acc0);
        acc1 = fmaf(x1.x, w.x, acc1); acc1 = fmaf(x1.y, w.y, acc1); acc1 = fmaf(x1.z, w.z, acc1); acc1 = fmaf(x1.w, w.w, acc1);
        acc2 = fmaf(x2.x, w.x, acc2); acc2 = fmaf(x2.y, w.y, acc2); acc2 = fmaf(x2.z, w.z, acc2); acc2 = fmaf(x2.w, w.w, acc2);
        acc3 = fmaf(x3.x, w.x, acc3); acc3 = fmaf(x3.y, w.y, acc3); acc3 = fmaf(x3.z, w.z, acc3); acc3 = fmaf(x3.w, w.w, acc3);
    }
    const float bb = b[t];
    float v[4] = {fmaxf(acc0 + bb, 0.f), fmaxf(acc1 + bb, 0.f), fmaxf(acc2 + bb, 0.f), fmaxf(acc3 + bb, 0.f)};
    short hv[4];
    #pragma unroll
    for (int r = 0; r < 4; ++r) hv[r] = h16s(v[r]);
    #pragma unroll
    for (int r = 0; r < 4; ++r) {
        const int row = r0 + r;
        if (row < SE) { emo[(size_t)row * D + t] = v[r]; emoH[(size_t)row * D + t] = hv[r]; }
        else { cau[(size_t)(row - SE) * D + t] = v[r]; cauH[(size_t)(row - SE) * D + t] = hv[r]; }
    }
    // fused row sum-of-squares on the f16-rounded values
    __shared__ float rsum[4][4];
    #pragma unroll
    for (int r = 0; r < 4; ++r) {
        const float f = h16f(hv[r]);
        float s = f * f;
        s += __shfl_xor(s, 1);  s += __shfl_xor(s, 2);
        s += __shfl_xor(s, 4);  s += __shfl_xor(s, 8);
        s += __shfl_xor(s, 16); s += __shfl_xor(s, 32);
        if ((t & 63) == 0) rsum[r][t >> 6] = s;
    }
    __syncthreads();
    if (t < 4) {
        const float tot = rsum[t][0] + rsum[t][1] + rsum[t][2] + rsum[t][3];
        const int row = r0 + t;
        if (row < SE) se2[row] = tot; else sc2[row - SE] = tot;
    }
}

// ============ GX = cau @ Wih + bih, 2 rows/block ============
__global__ __launch_bounds__(768) void gx2_kernel(
    const float* __restrict__ cau, const uint2* __restrict__ Wih16,
    const float* __restrict__ bih, __half* __restrict__ GX16)
{
    const int r0 = blockIdx.x * 2, t = threadIdx.x;
    __shared__ uint2 xs4[2][64];
    if (t < 128) {
        const int r = t >> 6, c = t & 63;
        float4 v = *(const float4*)&cau[(size_t)(r0 + r) * D + c * 4];
        __half2 plo = __halves2half2(__float2half_rn(v.x), __float2half_rn(v.y));
        __half2 phi = __halves2half2(__float2half_rn(v.z), __float2half_rn(v.w));
        uint2 o; o.x = *(unsigned int*)&plo; o.y = *(unsigned int*)&phi;
        xs4[r][c] = o;
    }
    __syncthreads();
    __half2 a00 = __float2half2_rn(0.f), a01 = __float2half2_rn(0.f);
    __half2 a10 = __float2half2_rn(0.f), a11 = __float2half2_rn(0.f);
    #pragma unroll 8
    for (int q = 0; q < 64; ++q) {
        uint2 w = Wih16[q * 768 + t];
        uint2 x0 = xs4[0][q], x1 = xs4[1][q];
        a00 = __hfma2(*(__half2*)&w.x, *(__half2*)&x0.x, a00);
        a01 = __hfma2(*(__half2*)&w.y, *(__half2*)&x0.y, a01);
        a10 = __hfma2(*(__half2*)&w.x, *(__half2*)&x1.x, a10);
        a11 = __hfma2(*(__half2*)&w.y, *(__half2*)&x1.y, a11);
    }
    const float bi = bih[t];
    float g0 = bi + __low2float(a00) + __high2float(a00) + __low2float(a01) + __high2float(a01);
    float g1 = bi + __low2float(a10) + __high2float(a10) + __low2float(a11) + __high2float(a11);
    GX16[(size_t)r0 * 768 + t] = __float2half_rn(g0);
    GX16[(size_t)(r0 + 1) * 768 + t] = __float2half_rn(g1);
}

// ============ GRU recurrence, Whh register-resident ============
__global__ __launch_bounds__(768) void gru_rec_kernel(
    const __half* __restrict__ GX16, const uint2* __restrict__ Whh16,
    const float* __restrict__ bhh, float* __restrict__ ch_last)
{
    const int c = blockIdx.x, t = threadIdx.x;
    __shared__ uint2 hqu[64];
    __shared__ float gh_s[768];
    uint2 wreg[64];
    #pragma unroll
    for (int q = 0; q < 64; ++q) wreg[q] = Whh16[q * 768 + t];
    float h = 0.f;
    if (t < 64) { uint2 z; z.x = 0u; z.y = 0u; hqu[t] = z; }
    __syncthreads();
    const float bh = bhh[t];
    for (int s = 0; s < CKS; ++s) {
        const int row = c * CKS + s;
        __half2 a0 = __float2half2_rn(0.f), a1 = __float2half2_rn(0.f);
        #pragma unroll
        for (int q = 0; q < 64; ++q) {
            uint2 hv = hqu[q];
            a0 = __hfma2(*(__half2*)&wreg[q].x, *(__half2*)&hv.x, a0);
            a1 = __hfma2(*(__half2*)&wreg[q].y, *(__half2*)&hv.y, a1);
        }
        gh_s[t] = bh + __low2float(a0) + __high2float(a0) + __low2float(a1) + __high2float(a1);
        __syncthreads();
        if (t < 256) {
            const float gxr = __half2float(GX16[(size_t)row * 768 + t]);
            const float gxz = __half2float(GX16[(size_t)row * 768 + 256 + t]);
            const float gxn = __half2float(GX16[(size_t)row * 768 + 512 + t]);
            float r = sigmoidf_(gxr + gh_s[t]);
            float z = sigmoidf_(gxz + gh_s[256 + t]);
            float n = tanhf(gxn + r * gh_s[512 + t]);
            h = (1.f - z) * n + z * h;
            float f1 = __shfl_down(h, 1);
            float f2 = __shfl_down(h, 2);
            float f3 = __shfl_down(h, 3);
            if ((t & 3) == 0) {
                __half2 plo = __halves2half2(__float2half_rn(h),  __float2half_rn(f1));
                __half2 phi = __halves2half2(__float2half_rn(f2), __float2half_rn(f3));
                uint2 o; o.x = *(unsigned int*)&plo; o.y = *(unsigned int*)&phi;
                hqu[t >> 2] = o;
            }
        }
        __syncthreads();
    }
    if (t < 256) ch_last[c * D + t] = h;
}

// ============ merged linears, 4 rows/block ============
__global__ __launch_bounds__(256) void dual_all4_kernel(
    const float* __restrict__ emo, const float* __restrict__ cau, const float* __restrict__ chl,
    const float4* __restrict__ WWq, const float4* __restrict__ W3q,
    const float* __restrict__ Wb, const float* __restrict__ W3b,
    float* __restrict__ HE, float* __restrict__ HC, float* __restrict__ Ae,
    short* __restrict__ AcB)
{
    const int r0 = blockIdx.x * 4, t = threadIdx.x;
    const float* X; const float4* Wq; float bias;
    int seg;
    if (r0 < 512)       { X = emo + (size_t)r0 * D;          Wq = WWq;         bias = 0.f;    seg = 0; }
    else if (r0 < 576)  { X = chl + (size_t)(r0 - 512) * D;  Wq = WWq + 16384; bias = Wb[t];  seg = 1; }
    else if (r0 < 1088) { X = emo + (size_t)(r0 - 576) * D;  Wq = W3q;         bias = 0.f;    seg = 2; }
    else                { X = cau + (size_t)(r0 - 1088) * D; Wq = W3q + 16384; bias = W3b[t]; seg = 3; }
    __shared__ __align__(16) float xs[4][D];
    #pragma unroll
    for (int r = 0; r < 4; ++r) xs[r][t] = X[r * D + t];
    __syncthreads();
    float a0 = bias, a1 = bias, a2 = bias, a3 = bias;
    #pragma unroll 8
    for (int q = 0; q < 64; ++q) {
        float4 w = Wq[q * 256 + t];
        float4 x0 = *(const float4*)&xs[0][q * 4];
        float4 x1 = *(const float4*)&xs[1][q * 4];
        float4 x2 = *(const float4*)&xs[2][q * 4];
        float4 x3 = *(const float4*)&xs[3][q * 4];
        a0 = fmaf(x0.x, w.x, a0); a0 = fmaf(x0.y, w.y, a0); a0 = fmaf(x0.z, w.z, a0); a0 = fmaf(x0.w, w.w, a0);
        a1 = fmaf(x1.x, w.x, a1); a1 = fmaf(x1.y, w.y, a1); a1 = fmaf(x1.z, w.z, a1); a1 = fmaf(x1.w, w.w, a1);
        a2 = fmaf(x2.x, w.x, a2); a2 = fmaf(x2.y, w.y, a2); a2 = fmaf(x2.z, w.z, a2); a2 = fmaf(x2.w, w.w, a2);
        a3 = fmaf(x3.x, w.x, a3); a3 = fmaf(x3.y, w.y, a3); a3 = fmaf(x3.z, w.z, a3); a3 = fmaf(x3.w, w.w, a3);
    }
    float av[4] = {a0, a1, a2, a3};
    #pragma unroll
    for (int r = 0; r < 4; ++r) {
        const int row = r0 + r;
        if (seg == 0)      HE[(size_t)row * D + t] = av[r];
        else if (seg == 1) HC[(size_t)(row - 512) * D + t] = av[r];
        else if (seg == 2) Ae[(size_t)(row - 576) * D + t] = av[r];
        else               AcB[(size_t)(row - 1088) * D + t] = bf16s(av[r]);
    }
}

// ============ phase2 ============
__global__ __launch_bounds__(256) void phase2_kernel(
    const float* __restrict__ HE, const float* __restrict__ HC,
    const float* __restrict__ WoW, const float* __restrict__ Wob,
    float* __restrict__ out)
{
    const int i = blockIdx.x, t = threadIdx.x;
    const int c = t >> 2, sub = t & 3;
    __shared__ __align__(16) float he_s[D];
    he_s[t] = HE[(size_t)i * D + t];
    __syncthreads();
    float v0 = 0.f, v1 = 0.f;
    const float* hcRow = HC + (size_t)c * D;
    #pragma unroll 4
    for (int kk = 0; kk < 16; ++kk) {
        const int k4 = sub * 64 + kk * 4;
        float4 he = *(const float4*)&he_s[k4];
        float4 hc = *(const float4*)&hcRow[k4];
        float hk;
        hk = sigmoidf_(he.x + hc.x); { float2 wo = *(const float2*)&WoW[(k4 + 0) * 2]; v0 = fmaf(hk, wo.x, v0); v1 = fmaf(hk, wo.y, v1); }
        hk = sigmoidf_(he.y + hc.y); { float2 wo = *(const float2*)&WoW[(k4 + 1) * 2]; v0 = fmaf(hk, wo.x, v0); v1 = fmaf(hk, wo.y, v1); }
        hk = sigmoidf_(he.z + hc.z); { float2 wo = *(const float2*)&WoW[(k4 + 2) * 2]; v0 = fmaf(hk, wo.x, v0); v1 = fmaf(hk, wo.y, v1); }
        hk = sigmoidf_(he.w + hc.w); { float2 wo = *(const float2*)&WoW[(k4 + 3) * 2]; v0 = fmaf(hk, wo.x, v0); v1 = fmaf(hk, wo.y, v1); }
    }
    v0 += __shfl_xor(v0, 1); v0 += __shfl_xor(v0, 2);
    v1 += __shfl_xor(v1, 1); v1 += __shfl_xor(v1, 2);
    if (sub == 0) {
        float l0 = v0 + Wob[0], l1 = v1 + Wob[1];
        float m = fmaxf(l0, l1);
        float lse = m + __logf(__expf(l0 - m) + __expf(l1 - m));
        float2 o; o.x = l0 - lse; o.y = l1 - lse;
        *(float2*)&out[((size_t)i * NC + c) * 2] = o;
    }
}

// ============ p v18: fp16 + ii-pairing (1 ds_read feeds 2 MFMAs) ============
// grid (32 i-chunks of 16, 8 jt x 2 kh); 8 waves = 4wj x 2wk; wave 16j x 64k
__global__ __launch_bounds__(512) void p_kernel(
    const short* __restrict__ emoH, const float* __restrict__ se2, const float* __restrict__ sc2,
    const float* __restrict__ Ae,  const short* __restrict__ AcB,
    const float* __restrict__ wn,  const short* __restrict__ Bprep,
    const short* __restrict__ cauH, const float* __restrict__ clsW,
    float* __restrict__ pp)   // partial [kh<2][i][j][2]
{
    const int t = threadIdx.x;
    const int i0 = blockIdx.x * 8;
    const int jt = blockIdx.y >> 1, kh = blockIdx.y & 1;
    const int j0 = jt * 64;
    const int l = t & 63, wave = t >> 6;
    const int hi = l >> 4, lo = l & 15;
    const int wj = wave >> 1, wk = wave & 1;
    const int j_base = wj * 16, k_base = wk * 64;   // k_base LOCAL (0..127)
    const int myj = j0 + j_base + lo;

    __shared__ __align__(16) short B_s[32768];   // 64 KB: [p<4][klocal<128][G<8][e<8] (f16)
    __shared__ float part2[64][2][2];

    // stage this k-half of B (linear dest, pre-swizzled source)
    #pragma unroll
    for (int r = 0; r < 8; ++r) {
        const int g = r * 512 + t;
        const int p = g >> 10, rem = g & 1023;
        GLOAD_LDS16(Bprep + ((size_t)(p * 256 + kh * 128) * 8 + rem) * 8, &B_s[g * 8]);
    }

    int kcol[4]; float wn_r[4], c0_r[4], c1_r[4];
    #pragma unroll
    for (int kf = 0; kf < 4; ++kf) {
        const int kg = kh * 128 + k_base + kf * 16 + lo;
        kcol[kf] = kg;
        wn_r[kf] = wn[kg];
        c0_r[kf] = clsW[kg * 2]; c1_r[kf] = clsW[kg * 2 + 1];
    }
    const int swzf0 = (hi ^ (lo & 7)) << 3;
    const int swzf1 = ((4 + hi) ^ (lo & 7)) << 3;
    const float sc2_l = sc2[myj];
    float Ac_r[4][4];
    #pragma unroll
    for (int q = 0; q < 4; ++q)
        #pragma unroll
        for (int kf = 0; kf < 4; ++kf)
            Ac_r[q][kf] = bflo((unsigned int)(unsigned short)AcB[(size_t)(j0 + j_base + hi * 4 + q) * D + kcol[kf]]);

    // this lane's 8 raw cau f16 frags (row myj) -> 32 VGPR, i-invariant
    uint4 cfr[8];
    #pragma unroll
    for (int s = 0; s < 8; ++s) {
        const int p = s >> 1, df = s & 1;
        cfr[s] = *(const uint4*)&cauH[(size_t)myj * D + p * 64 + (df * 4 + hi) * 8];
    }
    __syncthreads();   // B resident

    #pragma unroll 1
    for (int ii = 0; ii < 8; ii += 2) {
        __syncthreads();   // LICM fence for B_s reads + part2 reuse guard
        f32x4 acc[2][4];
        #pragma unroll
        for (int u = 0; u < 2; ++u)
            #pragma unroll
            for (int kf = 0; kf < 4; ++kf) acc[u][kf] = (f32x4)(0.f);
        float dot0 = 0.f, dot1 = 0.f;

        #pragma unroll
        for (int s = 0; s < 8; ++s) {
            const int p = s >> 1, df = s & 1;
            const uint4 eu0 = *(const uint4*)&emoH[(size_t)(i0 + ii) * D + p * 64 + (df * 4 + hi) * 8];
            const uint4 eu1 = *(const uint4*)&emoH[(size_t)(i0 + ii + 1) * D + p * 64 + (df * 4 + hi) * 8];
            const uint4 cu = cfr[s];
            const h2_t c0 = h2u(cu.x), c1 = h2u(cu.y), c2 = h2u(cu.z), c3 = h2u(cu.w);
            const h2_t a0 = h2u(eu0.x), a1 = h2u(eu0.y), a2 = h2u(eu0.z), a3 = h2u(eu0.w);
            const h2_t b0 = h2u(eu1.x), b1 = h2u(eu1.y), b2 = h2u(eu1.z), b3 = h2u(eu1.w);
            dot0 = hdot2(a0, c0, dot0); dot0 = hdot2(a1, c1, dot0);
            dot0 = hdot2(a2, c2, dot0); dot0 = hdot2(a3, c3, dot0);
            dot1 = hdot2(b0, c0, dot1); dot1 = hdot2(b1, c1, dot1);
            dot1 = hdot2(b2, c2, dot1); dot1 = hdot2(b3, c3, dot1);
            union { uint4 u; h8_t h; } af0, af1;
            af0.u.x = u2h(a0 * c0); af0.u.y = u2h(a1 * c1);
            af0.u.z = u2h(a2 * c2); af0.u.w = u2h(a3 * c3);
            af1.u.x = u2h(b0 * c0); af1.u.y = u2h(b1 * c1);
            af1.u.z = u2h(b2 * c2); af1.u.w = u2h(b3 * c3);
            const int swz = df ? swzf1 : swzf0;
            #pragma unroll
            for (int kf = 0; kf < 4; ++kf) {
                const h8_t bf = *(const h8_t*)&B_s[p * 8192 + (k_base + kf * 16 + lo) * 64 + swz];
                acc[0][kf] = __builtin_amdgcn_mfma_f32_16x16x32_f16(af0.h, bf, acc[0][kf], 0, 0, 0);
                acc[1][kf] = __builtin_amdgcn_mfma_f32_16x16x32_f16(af1.h, bf, acc[1][kf], 0, 0, 0);
            }
        }

        #pragma unroll
        for (int u = 0; u < 2; ++u) {
            const int i = i0 + ii + u;
            float dv = u ? dot1 : dot0;
            dv += __shfl_xor(dv, 16); dv += __shfl_xor(dv, 32);
            const float itv_own = sqrtf(fmaxf(se2[i] + sc2_l - 2.f * dv, 0.f));   // for row lo
            float Ae_r[4];
            #pragma unroll
            for (int kf = 0; kf < 4; ++kf) Ae_r[kf] = Ae[(size_t)i * D + kcol[kf]];
            if (u) __syncthreads();   // part2 of u=0 fully consumed
            #pragma unroll
            for (int q = 0; q < 4; ++q) {
                const int j = j_base + hi * 4 + q;
                const float itv = __shfl(itv_own, hi * 4 + q);
                float sv0 = 0.f, sv1 = 0.f;
                #pragma unroll
                for (int kf = 0; kf < 4; ++kf) {
                    float s = acc[u][kf][q] + Ae_r[kf] + Ac_r[q][kf] + itv * wn_r[kf];
                    float h = fmaxf(s, 0.f);
                    sv0 = fmaf(h, c0_r[kf], sv0); sv1 = fmaf(h, c1_r[kf], sv1);
                }
                sv0 += __shfl_xor(sv0, 1); sv0 += __shfl_xor(sv0, 2);
                sv0 += __shfl_xor(sv0, 4); sv0 += __shfl_xor(sv0, 8);
                sv1 += __shfl_xor(sv1, 1); sv1 += __shfl_xor(sv1, 2);
                sv1 += __shfl_xor(sv1, 4); sv1 += __shfl_xor(sv1, 8);
                if (lo == 0) { part2[j][wk][0] = sv0; part2[j][wk][1] = sv1; }
            }
            __syncthreads();   // part2 ready
            if (t < 64) {
                float2 o;
                o.x = part2[t][0][0] + part2[t][1][0];
                o.y = part2[t][0][1] + part2[t][1][1];
                *(float2*)&pp[(((size_t)kh * SE + i) * SC + j0 + t) * 2] = o;
            }
        }
    }
}

// ============ pfin: combine k-halves + log_softmax ============
__global__ __launch_bounds__(512) void pfin_kernel(
    const float* __restrict__ pp, const float* __restrict__ clsb,
    float* __restrict__ pout)
{
    const int i = blockIdx.x, j = threadIdx.x;
    const float2 a = *(const float2*)&pp[((size_t)i * SC + j) * 2];
    const float2 b = *(const float2*)&pp[(((size_t)SE + i) * SC + j) * 2];
    float s0 = a.x + b.x + clsb[0];
    float s1 = a.y + b.y + clsb[1];
    float m = fmaxf(s0, s1);
    float lse = m + __logf(__expf(s0 - m) + __expf(s1 - m));
    float2 o; o.x = s0 - lse; o.y = s1 - lse;
    *(float2*)&pout[((size_t)i * SC + j) * 2] = o;
}

// ============ L_cau ============
__global__ __launch_bounds__(128) void lcau_kernel(const int* __restrict__ label3, float* __restrict__ L)
{
    const int row = blockIdx.x, t = threadIdx.x;
    float4 z; z.x = z.y = z.z = z.w = 0.f;
    *(float4*)&L[(size_t)row * SC + t * 4] = z;
    __syncthreads();
    if (t < KC) {
        int j = label3[row * KC + t];
        L[(size_t)row * SC + j] = 1.0f;
    }
}

extern "C" void kernel_launch(void* const* d_in, const int* in_sizes, int n_in,
                              void* d_out, int out_size, void* d_ws, size_t ws_size,
                              hipStream_t stream)
{
    const float* text_emo = (const float*)d_in[0];
    const float* text_cau = (const float*)d_in[1];
    const int*   label3   = (const int*)d_in[3];
    const float* rep_W = (const float*)d_in[5];
    const float* rep_b = (const float*)d_in[6];
    const float* W_W   = (const float*)d_in[7];
    const float* W_b   = (const float*)d_in[8];
    const float* Wo_W  = (const float*)d_in[9];
    const float* Wo_b  = (const float*)d_in[10];
    const float* gWih  = (const float*)d_in[11];
    const float* gWhh  = (const float*)d_in[12];
    const float* gbih  = (const float*)d_in[13];
    const float* gbhh  = (const float*)d_in[14];
    const float* W3_W  = (const float*)d_in[15];
    const float* W3_b  = (const float*)d_in[16];
    const float* cls_W = (const float*)d_in[17];
    const float* cls_b = (const float*)d_in[18];

    float* out        = (float*)d_out;
    float* phase2_out = out;
    float* p_out      = out + SE * NC * 2;
    float* lcau_out   = out + SE * NC * 2 + SE * SC * 2;

    // workspace layout (floats): ~9.5 MB total
    float* ws  = (float*)d_ws;
    float* emo = ws;                           // 131072
    float* cau = emo + 131072;                 // 131072
    float* chl = cau + 131072;                 // 16384
    float* HE  = chl + 16384;                  // 131072
    float* HC  = HE + 131072;                  // 16384
    float* Ae  = HC + 16384;                   // 131072
    float4* WWq = (float4*)(Ae + 131072);      // 32768 f4
    float4* W3q = WWq + 32768;                 // 32768 f4
    short* AcB   = (short*)(W3q + 32768);      // 131072 bf16
    short* Bprep = AcB + 131072;               // 65536 (f16)
    uint2* Wih16 = (uint2*)(Bprep + 65536);    // 49152 u2
    uint2* Whh16 = Wih16 + 49152;              // 49152 u2
    float4* repWq = (float4*)(Whh16 + 49152);  // 16384 f4
    short* cauH = (short*)(repWq + 16384);     // 131072 f16
    short* emoH = cauH + 131072;               // 131072 f16
    unsigned int* clsP = (unsigned int*)(emoH + 131072);  // 256
    float* pp = (float*)(clsP + 256);          // 1048576 f: [2][512][512][2]
    float* sc2 = pp + 1048576;                 // 512
    float* se2 = sc2 + 512;                    // 512
    __half* GX16 = (__half*)HE;                // overlays HE/HC/Ae

    prep_all_kernel<<<737, 256, 0, stream>>>(W3_W, gWih, gWhh, W_W, rep_W, cls_W,
                                             Bprep, Wih16, Whh16, WWq, W3q, repWq, clsP);
    rep4_kernel<<<256, 256, 0, stream>>>(text_emo, text_cau, repWq, rep_b, emo, cau,
                                         emoH, cauH, se2, sc2);
    gx2_kernel<<<256, 768, 0, stream>>>(cau, Wih16, gbih, GX16);
    gru_rec_kernel<<<NC, 768, 0, stream>>>(GX16, Whh16, gbhh, chl);
    dual_all4_kernel<<<400, 256, 0, stream>>>(emo, cau, chl, WWq, W3q, W_b, W3_b,
                                              HE, HC, Ae, AcB);
    phase2_kernel<<<SE, 256, 0, stream>>>(HE, HC, Wo_W, Wo_b, phase2_out);
    p_kernel<<<dim3(64, 16), 512, 0, stream>>>(emoH, se2, sc2, Ae, AcB, W3_W + 512 * D,
                                               Bprep, cauH, cls_W, pp);
    pfin_kernel<<<SE, 512, 0, stream>>>(pp, cls_b, p_out);
    lcau_kernel<<<SE, 128, 0, stream>>>(label3, lcau_out);
}

// Round 19
// 167.991 us; speedup vs baseline: 1.0244x; 1.0244x over previous
//
#include <hip/hip_runtime.h>
#include <hip/hip_bf16.h>
#include <hip/hip_fp16.h>
#include <math.h>

#define D   256
#define SE  512
#define SC  512
#define CKS 8
#define NC  64   // SC / CKS
#define KC  3

typedef __attribute__((ext_vector_type(8))) short short8_t;
typedef __attribute__((ext_vector_type(4))) float f32x4;
typedef _Float16 h2_t __attribute__((ext_vector_type(2)));
typedef _Float16 h8_t __attribute__((ext_vector_type(8)));

__device__ __forceinline__ float sigmoidf_(float x) { return 1.f / (1.f + __expf(-x)); }
__device__ __forceinline__ short bf16s(float f) {
    union { __hip_bfloat16 h; short s; } u; u.h = __float2bfloat16(f); return u.s;
}
__device__ __forceinline__ float bflo(unsigned int u) {
    union { unsigned int u; float f; } v; v.u = u << 16; return v.f;
}
__device__ __forceinline__ short h16s(float f) {
    union { _Float16 h; short s; } u; u.h = (_Float16)f; return u.s;
}
__device__ __forceinline__ float h16f(short s) {
    union { short s; _Float16 h; } u; u.s = s; return (float)u.h;
}
__device__ __forceinline__ h2_t h2u(unsigned int u) {
    union { unsigned int u; h2_t h; } v; v.u = u; return v.h;
}
__device__ __forceinline__ unsigned int u2h(h2_t h) {
    union { unsigned int u; h2_t h; } v; v.h = h; return v.u;
}
__device__ __forceinline__ float hdot2(h2_t a, h2_t b, float c) {
#if __has_builtin(__builtin_amdgcn_fdot2)
    return __builtin_amdgcn_fdot2(a, b, c, false);
#else
    h2_t p = a * b;
    return c + (float)p[0] + (float)p[1];
#endif
}
#define GLOAD_LDS16(g, l) \
    __builtin_amdgcn_global_load_lds((const __attribute__((address_space(1))) void*)(g), \
                                     (__attribute__((address_space(3))) void*)(l), 16, 0, 0)

// ============ prep: all weight conversions ============
__global__ __launch_bounds__(256) void prep_all_kernel(
    const float* __restrict__ W3, const float* __restrict__ Wih,
    const float* __restrict__ Whh, const float* __restrict__ WW,
    const float* __restrict__ repW, const float* __restrict__ clsW,
    short* __restrict__ Bprep, uint2* __restrict__ Wih16, uint2* __restrict__ Whh16,
    float4* __restrict__ WWq, float4* __restrict__ W3q,
    float4* __restrict__ repWq, unsigned int* __restrict__ clsP)
{
    const int b = blockIdx.x, t = threadIdx.x;
    if (b < 32) {
        const int idx = b * 256 + t;
        const int p = idx >> 11, k = (idx >> 3) & 255, G = idx & 7;
        const int dbase = p * 64 + ((G ^ (k & 7)) << 3);
        #pragma unroll
        for (int e = 0; e < 8; ++e)
            Bprep[idx * 8 + e] = h16s(W3[(size_t)(513 + dbase + e) * D + k]);   // fp16
    } else if (b < 416) {
        const bool ih = (b < 224);
        const int tid = (b - (ih ? 32 : 224)) * 256 + t;
        const float* W = ih ? Wih : Whh;
        const int base = (tid / 768) * 4 * 768 + (tid % 768);
        float f0 = W[base], f1 = W[base + 768], f2 = W[base + 1536], f3 = W[base + 2304];
        __half2 plo = __halves2half2(__float2half_rn(f0), __float2half_rn(f1));
        __half2 phi = __halves2half2(__float2half_rn(f2), __float2half_rn(f3));
        uint2 o; o.x = *(unsigned int*)&plo; o.y = *(unsigned int*)&phi;
        (ih ? Wih16 : Whh16)[tid] = o;
    } else if (b < 672) {
        const bool ww = (b < 544);
        const int tid = (b - (ww ? 416 : 544)) * 256 + t;
        const int h = tid >> 14, rem = tid & 16383, d4 = rem >> 8, k = rem & 255;
        const float* src = (ww ? WW : W3) + (size_t)(h * 256 + 4 * d4) * D + k;
        (ww ? WWq : W3q)[tid] = make_float4(src[0], src[256], src[512], src[768]);
    } else if (b < 736) {
        const int tid = (b - 672) * 256 + t;
        const int d4 = tid >> 8, k = tid & 255;
        const float* src = repW + (size_t)(4 * d4) * D + k;
        repWq[tid] = make_float4(src[0], src[256], src[512], src[768]);
    } else {
        unsigned int c0 = (unsigned int)(unsigned short)bf16s(clsW[t * 2]);
        unsigned int c1 = (unsigned int)(unsigned short)bf16s(clsW[t * 2 + 1]);
        clsP[t] = c0 | (c1 << 16);
    }
}

// ============ rep8: 8 rows/block (f32 + f16 outputs) + fused sq-sums ============
__global__ __launch_bounds__(256) void rep8_kernel(
    const float* __restrict__ te, const float* __restrict__ tc,
    const float4* __restrict__ repWq, const float* __restrict__ b,
    float* __restrict__ emo, float* __restrict__ cau,
    short* __restrict__ emoH, short* __restrict__ cauH,
    float* __restrict__ se2, float* __restrict__ sc2)
{
    const int r0 = blockIdx.x * 8, t = threadIdx.x;
    const float* X = (r0 < SE) ? (te + (size_t)r0 * D) : (tc + (size_t)(r0 - SE) * D);
    __shared__ __align__(16) float xs[8][D];
    #pragma unroll
    for (int r = 0; r < 8; ++r) xs[r][t] = X[r * D + t];
    __syncthreads();
    float acc[8];
    #pragma unroll
    for (int r = 0; r < 8; ++r) acc[r] = 0.f;
    #pragma unroll 4
    for (int q = 0; q < 64; ++q) {
        float4 w = repWq[q * 256 + t];
        #pragma unroll
        for (int r = 0; r < 8; ++r) {
            float4 x = *(const float4*)&xs[r][q * 4];
            acc[r] = fmaf(x.x, w.x, acc[r]); acc[r] = fmaf(x.y, w.y, acc[r]);
            acc[r] = fmaf(x.z, w.z, acc[r]); acc[r] = fmaf(x.w, w.w, acc[r]);
        }
    }
    const float bb = b[t];
    short hv[8];
    #pragma unroll
    for (int r = 0; r < 8; ++r) {
        const float v = fmaxf(acc[r] + bb, 0.f);
        hv[r] = h16s(v);
        const int row = r0 + r;
        if (row < SE) { emo[(size_t)row * D + t] = v; emoH[(size_t)row * D + t] = hv[r]; }
        else { cau[(size_t)(row - SE) * D + t] = v; cauH[(size_t)(row - SE) * D + t] = hv[r]; }
    }
    // fused row sum-of-squares on the f16-rounded values
    __shared__ float rsum[8][4];
    #pragma unroll
    for (int r = 0; r < 8; ++r) {
        const float f = h16f(hv[r]);
        float s = f * f;
        s += __shfl_xor(s, 1);  s += __shfl_xor(s, 2);
        s += __shfl_xor(s, 4);  s += __shfl_xor(s, 8);
        s += __shfl_xor(s, 16); s += __shfl_xor(s, 32);
        if ((t & 63) == 0) rsum[r][t >> 6] = s;
    }
    __syncthreads();
    if (t < 8) {
        const float tot = rsum[t][0] + rsum[t][1] + rsum[t][2] + rsum[t][3];
        const int row = r0 + t;
        if (row < SE) se2[row] = tot; else sc2[row - SE] = tot;
    }
}

// ============ GX = cau @ Wih + bih, 4 rows/block ============
__global__ __launch_bounds__(768) void gx4_kernel(
    const float* __restrict__ cau, const uint2* __restrict__ Wih16,
    const float* __restrict__ bih, __half* __restrict__ GX16)
{
    const int r0 = blockIdx.x * 4, t = threadIdx.x;
    __shared__ uint2 xs4[4][64];
    if (t < 256) {
        const int r = t >> 6, c = t & 63;
        float4 v = *(const float4*)&cau[(size_t)(r0 + r) * D + c * 4];
        __half2 plo = __halves2half2(__float2half_rn(v.x), __float2half_rn(v.y));
        __half2 phi = __halves2half2(__float2half_rn(v.z), __float2half_rn(v.w));
        uint2 o; o.x = *(unsigned int*)&plo; o.y = *(unsigned int*)&phi;
        xs4[r][c] = o;
    }
    __syncthreads();
    __half2 a[4][2];
    #pragma unroll
    for (int r = 0; r < 4; ++r) { a[r][0] = __float2half2_rn(0.f); a[r][1] = __float2half2_rn(0.f); }
    #pragma unroll 4
    for (int q = 0; q < 64; ++q) {
        uint2 w = Wih16[q * 768 + t];
        #pragma unroll
        for (int r = 0; r < 4; ++r) {
            uint2 x = xs4[r][q];
            a[r][0] = __hfma2(*(__half2*)&w.x, *(__half2*)&x.x, a[r][0]);
            a[r][1] = __hfma2(*(__half2*)&w.y, *(__half2*)&x.y, a[r][1]);
        }
    }
    const float bi = bih[t];
    #pragma unroll
    for (int r = 0; r < 4; ++r) {
        float g = bi + __low2float(a[r][0]) + __high2float(a[r][0])
                     + __low2float(a[r][1]) + __high2float(a[r][1]);
        GX16[(size_t)(r0 + r) * 768 + t] = __float2half_rn(g);
    }
}

// ============ GRU recurrence, Whh register-resident ============
__global__ __launch_bounds__(768) void gru_rec_kernel(
    const __half* __restrict__ GX16, const uint2* __restrict__ Whh16,
    const float* __restrict__ bhh, float* __restrict__ ch_last)
{
    const int c = blockIdx.x, t = threadIdx.x;
    __shared__ uint2 hqu[64];
    __shared__ float gh_s[768];
    uint2 wreg[64];
    #pragma unroll
    for (int q = 0; q < 64; ++q) wreg[q] = Whh16[q * 768 + t];
    float h = 0.f;
    if (t < 64) { uint2 z; z.x = 0u; z.y = 0u; hqu[t] = z; }
    __syncthreads();
    const float bh = bhh[t];
    for (int s = 0; s < CKS; ++s) {
        const int row = c * CKS + s;
        __half2 a0 = __float2half2_rn(0.f), a1 = __float2half2_rn(0.f);
        #pragma unroll
        for (int q = 0; q < 64; ++q) {
            uint2 hv = hqu[q];
            a0 = __hfma2(*(__half2*)&wreg[q].x, *(__half2*)&hv.x, a0);
            a1 = __hfma2(*(__half2*)&wreg[q].y, *(__half2*)&hv.y, a1);
        }
        gh_s[t] = bh + __low2float(a0) + __high2float(a0) + __low2float(a1) + __high2float(a1);
        __syncthreads();
        if (t < 256) {
            const float gxr = __half2float(GX16[(size_t)row * 768 + t]);
            const float gxz = __half2float(GX16[(size_t)row * 768 + 256 + t]);
            const float gxn = __half2float(GX16[(size_t)row * 768 + 512 + t]);
            float r = sigmoidf_(gxr + gh_s[t]);
            float z = sigmoidf_(gxz + gh_s[256 + t]);
            float n = tanhf(gxn + r * gh_s[512 + t]);
            h = (1.f - z) * n + z * h;
            float f1 = __shfl_down(h, 1);
            float f2 = __shfl_down(h, 2);
            float f3 = __shfl_down(h, 3);
            if ((t & 3) == 0) {
                __half2 plo = __halves2half2(__float2half_rn(h),  __float2half_rn(f1));
                __half2 phi = __halves2half2(__float2half_rn(f2), __float2half_rn(f3));
                uint2 o; o.x = *(unsigned int*)&plo; o.y = *(unsigned int*)&phi;
                hqu[t >> 2] = o;
            }
        }
        __syncthreads();
    }
    if (t < 256) ch_last[c * D + t] = h;
}

// ============ merged linears, 8 rows/block ============
__global__ __launch_bounds__(256) void dual_all8_kernel(
    const float* __restrict__ emo, const float* __restrict__ cau, const float* __restrict__ chl,
    const float4* __restrict__ WWq, const float4* __restrict__ W3q,
    const float* __restrict__ Wb, const float* __restrict__ W3b,
    float* __restrict__ HE, float* __restrict__ HC, float* __restrict__ Ae,
    short* __restrict__ AcB)
{
    const int r0 = blockIdx.x * 8, t = threadIdx.x;
    const float* X; const float4* Wq; float bias;
    int seg;
    if (r0 < 512)       { X = emo + (size_t)r0 * D;          Wq = WWq;         bias = 0.f;    seg = 0; }
    else if (r0 < 576)  { X = chl + (size_t)(r0 - 512) * D;  Wq = WWq + 16384; bias = Wb[t];  seg = 1; }
    else if (r0 < 1088) { X = emo + (size_t)(r0 - 576) * D;  Wq = W3q;         bias = 0.f;    seg = 2; }
    else                { X = cau + (size_t)(r0 - 1088) * D; Wq = W3q + 16384; bias = W3b[t]; seg = 3; }
    __shared__ __align__(16) float xs[8][D];
    #pragma unroll
    for (int r = 0; r < 8; ++r) xs[r][t] = X[r * D + t];
    __syncthreads();
    float a[8];
    #pragma unroll
    for (int r = 0; r < 8; ++r) a[r] = bias;
    #pragma unroll 4
    for (int q = 0; q < 64; ++q) {
        float4 w = Wq[q * 256 + t];
        #pragma unroll
        for (int r = 0; r < 8; ++r) {
            float4 x = *(const float4*)&xs[r][q * 4];
            a[r] = fmaf(x.x, w.x, a[r]); a[r] = fmaf(x.y, w.y, a[r]);
            a[r] = fmaf(x.z, w.z, a[r]); a[r] = fmaf(x.w, w.w, a[r]);
        }
    }
    #pragma unroll
    for (int r = 0; r < 8; ++r) {
        const int row = r0 + r;
        if (seg == 0)      HE[(size_t)row * D + t] = a[r];
        else if (seg == 1) HC[(size_t)(row - 512) * D + t] = a[r];
        else if (seg == 2) Ae[(size_t)(row - 576) * D + t] = a[r];
        else               AcB[(size_t)(row - 1088) * D + t] = bf16s(a[r]);
    }
}

// ============ phase2 ============
__global__ __launch_bounds__(256) void phase2_kernel(
    const float* __restrict__ HE, const float* __restrict__ HC,
    const float* __restrict__ WoW, const float* __restrict__ Wob,
    float* __restrict__ out)
{
    const int i = blockIdx.x, t = threadIdx.x;
    const int c = t >> 2, sub = t & 3;
    __shared__ __align__(16) float he_s[D];
    he_s[t] = HE[(size_t)i * D + t];
    __syncthreads();
    float v0 = 0.f, v1 = 0.f;
    const float* hcRow = HC + (size_t)c * D;
    #pragma unroll 4
    for (int kk = 0; kk < 16; ++kk) {
        const int k4 = sub * 64 + kk * 4;
        float4 he = *(const float4*)&he_s[k4];
        float4 hc = *(const float4*)&hcRow[k4];
        float hk;
        hk = sigmoidf_(he.x + hc.x); { float2 wo = *(const float2*)&WoW[(k4 + 0) * 2]; v0 = fmaf(hk, wo.x, v0); v1 = fmaf(hk, wo.y, v1); }
        hk = sigmoidf_(he.y + hc.y); { float2 wo = *(const float2*)&WoW[(k4 + 1) * 2]; v0 = fmaf(hk, wo.x, v0); v1 = fmaf(hk, wo.y, v1); }
        hk = sigmoidf_(he.z + hc.z); { float2 wo = *(const float2*)&WoW[(k4 + 2) * 2]; v0 = fmaf(hk, wo.x, v0); v1 = fmaf(hk, wo.y, v1); }
        hk = sigmoidf_(he.w + hc.w); { float2 wo = *(const float2*)&WoW[(k4 + 3) * 2]; v0 = fmaf(hk, wo.x, v0); v1 = fmaf(hk, wo.y, v1); }
    }
    v0 += __shfl_xor(v0, 1); v0 += __shfl_xor(v0, 2);
    v1 += __shfl_xor(v1, 1); v1 += __shfl_xor(v1, 2);
    if (sub == 0) {
        float l0 = v0 + Wob[0], l1 = v1 + Wob[1];
        float m = fmaxf(l0, l1);
        float lse = m + __logf(__expf(l0 - m) + __expf(l1 - m));
        float2 o; o.x = l0 - lse; o.y = l1 - lse;
        *(float2*)&out[((size_t)i * NC + c) * 2] = o;
    }
}

// ============ p v17 (proven 84us): fp16 packed A-build + f16 MFMA ============
// grid (64 i-chunks, 8 jt x 2 kh); 8 waves = 4wj x 2wk; wave 16j x 64k
__global__ __launch_bounds__(512) void p_kernel(
    const short* __restrict__ emoH, const float* __restrict__ se2, const float* __restrict__ sc2,
    const float* __restrict__ Ae,  const short* __restrict__ AcB,
    const float* __restrict__ wn,  const short* __restrict__ Bprep,
    const short* __restrict__ cauH, const float* __restrict__ clsW,
    float* __restrict__ pp)   // partial [kh<2][i][j][2]
{
    const int t = threadIdx.x;
    const int i0 = blockIdx.x * 8;
    const int jt = blockIdx.y >> 1, kh = blockIdx.y & 1;
    const int j0 = jt * 64;
    const int l = t & 63, wave = t >> 6;
    const int hi = l >> 4, lo = l & 15;
    const int wj = wave >> 1, wk = wave & 1;
    const int j_base = wj * 16, k_base = wk * 64;   // k_base LOCAL (0..127)
    const int myj = j0 + j_base + lo;

    __shared__ __align__(16) short B_s[32768];   // 64 KB: [p<4][klocal<128][G<8][e<8] (f16)
    __shared__ float part2[64][2][2];

    // stage this k-half of B (linear dest, pre-swizzled source)
    #pragma unroll
    for (int r = 0; r < 8; ++r) {
        const int g = r * 512 + t;
        const int p = g >> 10, rem = g & 1023;
        GLOAD_LDS16(Bprep + ((size_t)(p * 256 + kh * 128) * 8 + rem) * 8, &B_s[g * 8]);
    }

    int kcol[4]; float wn_r[4], c0_r[4], c1_r[4];
    #pragma unroll
    for (int kf = 0; kf < 4; ++kf) {
        const int kg = kh * 128 + k_base + kf * 16 + lo;
        kcol[kf] = kg;
        wn_r[kf] = wn[kg];
        c0_r[kf] = clsW[kg * 2]; c1_r[kf] = clsW[kg * 2 + 1];
    }
    const int swzf0 = (hi ^ (lo & 7)) << 3;
    const int swzf1 = ((4 + hi) ^ (lo & 7)) << 3;
    const float sc2_l = sc2[myj];
    float Ac_r[4][4];
    #pragma unroll
    for (int q = 0; q < 4; ++q)
        #pragma unroll
        for (int kf = 0; kf < 4; ++kf)
            Ac_r[q][kf] = bflo((unsigned int)(unsigned short)AcB[(size_t)(j0 + j_base + hi * 4 + q) * D + kcol[kf]]);

    // this lane's 8 raw cau f16 frags (row myj) -> 32 VGPR, i-invariant
    uint4 cfr[8];
    #pragma unroll
    for (int s = 0; s < 8; ++s) {
        const int p = s >> 1, df = s & 1;
        cfr[s] = *(const uint4*)&cauH[(size_t)myj * D + p * 64 + (df * 4 + hi) * 8];
    }
    __syncthreads();   // B resident

    #pragma unroll 1
    for (int ii = 0; ii < 8; ++ii) {
        const int i = i0 + ii;
        __syncthreads();   // LICM fence for B_s reads + part2 reuse guard
        f32x4 acc[4];
        #pragma unroll
        for (int kf = 0; kf < 4; ++kf) acc[kf] = (f32x4)(0.f);
        float dot = 0.f;

        #pragma unroll
        for (int s = 0; s < 8; ++s) {
            const int p = s >> 1, df = s & 1;
            const uint4 eu = *(const uint4*)&emoH[(size_t)i * D + p * 64 + (df * 4 + hi) * 8];
            const uint4 cu = cfr[s];
            const h2_t e0 = h2u(eu.x), e1 = h2u(eu.y), e2 = h2u(eu.z), e3 = h2u(eu.w);
            const h2_t c0 = h2u(cu.x), c1 = h2u(cu.y), c2 = h2u(cu.z), c3 = h2u(cu.w);
            dot = hdot2(e0, c0, dot);
            dot = hdot2(e1, c1, dot);
            dot = hdot2(e2, c2, dot);
            dot = hdot2(e3, c3, dot);
            union { uint4 u; h8_t h; } afu;
            afu.u.x = u2h(e0 * c0);
            afu.u.y = u2h(e1 * c1);
            afu.u.z = u2h(e2 * c2);
            afu.u.w = u2h(e3 * c3);
            const int swz = df ? swzf1 : swzf0;
            #pragma unroll
            for (int kf = 0; kf < 4; ++kf) {
                const h8_t bf = *(const h8_t*)&B_s[p * 8192 + (k_base + kf * 16 + lo) * 64 + swz];
                acc[kf] = __builtin_amdgcn_mfma_f32_16x16x32_f16(afu.h, bf, acc[kf], 0, 0, 0);
            }
        }

        // it2 via dot identity (sum over hi groups)
        float dv = dot;
        dv += __shfl_xor(dv, 16); dv += __shfl_xor(dv, 32);
        const float itv_own = sqrtf(fmaxf(se2[i] + sc2_l - 2.f * dv, 0.f));   // for row lo

        // epilogue: partial cls-dot over this wave's 64 k
        float Ae_r[4];
        #pragma unroll
        for (int kf = 0; kf < 4; ++kf) Ae_r[kf] = Ae[(size_t)i * D + kcol[kf]];
        #pragma unroll
        for (int q = 0; q < 4; ++q) {
            const int j = j_base + hi * 4 + q;
            const float itv = __shfl(itv_own, hi * 4 + q);
            float sv0 = 0.f, sv1 = 0.f;
            #pragma unroll
            for (int kf = 0; kf < 4; ++kf) {
                float s = acc[kf][q] + Ae_r[kf] + Ac_r[q][kf] + itv * wn_r[kf];
                float h = fmaxf(s, 0.f);
                sv0 = fmaf(h, c0_r[kf], sv0); sv1 = fmaf(h, c1_r[kf], sv1);
            }
            sv0 += __shfl_xor(sv0, 1); sv0 += __shfl_xor(sv0, 2);
            sv0 += __shfl_xor(sv0, 4); sv0 += __shfl_xor(sv0, 8);
            sv1 += __shfl_xor(sv1, 1); sv1 += __shfl_xor(sv1, 2);
            sv1 += __shfl_xor(sv1, 4); sv1 += __shfl_xor(sv1, 8);
            if (lo == 0) { part2[j][wk][0] = sv0; part2[j][wk][1] = sv1; }
        }
        __syncthreads();   // part2 ready
        if (t < 64) {
            float2 o;
            o.x = part2[t][0][0] + part2[t][1][0];
            o.y = part2[t][0][1] + part2[t][1][1];
            *(float2*)&pp[(((size_t)kh * SE + i) * SC + j0 + t) * 2] = o;
        }
    }
}

// ============ pfin: combine k-halves + log_softmax ============
__global__ __launch_bounds__(512) void pfin_kernel(
    const float* __restrict__ pp, const float* __restrict__ clsb,
    float* __restrict__ pout)
{
    const int i = blockIdx.x, j = threadIdx.x;
    const float2 a = *(const float2*)&pp[((size_t)i * SC + j) * 2];
    const float2 b = *(const float2*)&pp[(((size_t)SE + i) * SC + j) * 2];
    float s0 = a.x + b.x + clsb[0];
    float s1 = a.y + b.y + clsb[1];
    float m = fmaxf(s0, s1);
    float lse = m + __logf(__expf(s0 - m) + __expf(s1 - m));
    float2 o; o.x = s0 - lse; o.y = s1 - lse;
    *(float2*)&pout[((size_t)i * SC + j) * 2] = o;
}

// ============ L_cau ============
__global__ __launch_bounds__(128) void lcau_kernel(const int* __restrict__ label3, float* __restrict__ L)
{
    const int row = blockIdx.x, t = threadIdx.x;
    float4 z; z.x = z.y = z.z = z.w = 0.f;
    *(float4*)&L[(size_t)row * SC + t * 4] = z;
    __syncthreads();
    if (t < KC) {
        int j = label3[row * KC + t];
        L[(size_t)row * SC + j] = 1.0f;
    }
}

extern "C" void kernel_launch(void* const* d_in, const int* in_sizes, int n_in,
                              void* d_out, int out_size, void* d_ws, size_t ws_size,
                              hipStream_t stream)
{
    const float* text_emo = (const float*)d_in[0];
    const float* text_cau = (const float*)d_in[1];
    const int*   label3   = (const int*)d_in[3];
    const float* rep_W = (const float*)d_in[5];
    const float* rep_b = (const float*)d_in[6];
    const float* W_W   = (const float*)d_in[7];
    const float* W_b   = (const float*)d_in[8];
    const float* Wo_W  = (const float*)d_in[9];
    const float* Wo_b  = (const float*)d_in[10];
    const float* gWih  = (const float*)d_in[11];
    const float* gWhh  = (const float*)d_in[12];
    const float* gbih  = (const float*)d_in[13];
    const float* gbhh  = (const float*)d_in[14];
    const float* W3_W  = (const float*)d_in[15];
    const float* W3_b  = (const float*)d_in[16];
    const float* cls_W = (const float*)d_in[17];
    const float* cls_b = (const float*)d_in[18];

    float* out        = (float*)d_out;
    float* phase2_out = out;
    float* p_out      = out + SE * NC * 2;
    float* lcau_out   = out + SE * NC * 2 + SE * SC * 2;

    // workspace layout (floats): ~9.5 MB total
    float* ws  = (float*)d_ws;
    float* emo = ws;                           // 131072
    float* cau = emo + 131072;                 // 131072
    float* chl = cau + 131072;                 // 16384
    float* HE  = chl + 16384;                  // 131072
    float* HC  = HE + 131072;                  // 16384
    float* Ae  = HC + 16384;                   // 131072
    float4* WWq = (float4*)(Ae + 131072);      // 32768 f4
    float4* W3q = WWq + 32768;                 // 32768 f4
    short* AcB   = (short*)(W3q + 32768);      // 131072 bf16
    short* Bprep = AcB + 131072;               // 65536 (f16)
    uint2* Wih16 = (uint2*)(Bprep + 65536);    // 49152 u2
    uint2* Whh16 = Wih16 + 49152;              // 49152 u2
    float4* repWq = (float4*)(Whh16 + 49152);  // 16384 f4
    short* cauH = (short*)(repWq + 16384);     // 131072 f16
    short* emoH = cauH + 131072;               // 131072 f16
    unsigned int* clsP = (unsigned int*)(emoH + 131072);  // 256
    float* pp = (float*)(clsP + 256);          // 1048576 f: [2][512][512][2]
    float* sc2 = pp + 1048576;                 // 512
    float* se2 = sc2 + 512;                    // 512
    __half* GX16 = (__half*)HE;                // overlays HE/HC/Ae

    prep_all_kernel<<<737, 256, 0, stream>>>(W3_W, gWih, gWhh, W_W, rep_W, cls_W,
                                             Bprep, Wih16, Whh16, WWq, W3q, repWq, clsP);
    rep8_kernel<<<128, 256, 0, stream>>>(text_emo, text_cau, repWq, rep_b, emo, cau,
                                         emoH, cauH, se2, sc2);
    gx4_kernel<<<128, 768, 0, stream>>>(cau, Wih16, gbih, GX16);
    gru_rec_kernel<<<NC, 768, 0, stream>>>(GX16, Whh16, gbhh, chl);
    dual_all8_kernel<<<200, 256, 0, stream>>>(emo, cau, chl, WWq, W3q, W_b, W3_b,
                                              HE, HC, Ae, AcB);
    phase2_kernel<<<SE, 256, 0, stream>>>(HE, HC, Wo_W, Wo_b, phase2_out);
    p_kernel<<<dim3(64, 16), 512, 0, stream>>>(emoH, se2, sc2, Ae, AcB, W3_W + 512 * D,
                                               Bprep, cauH, cls_W, pp);
    pfin_kernel<<<SE, 512, 0, stream>>>(pp, cls_b, p_out);
    lcau_kernel<<<SE, 128, 0, stream>>>(label3, lcau_out);
}

// Round 20
// 153.398 us; speedup vs baseline: 1.1218x; 1.0951x over previous
//
#include <hip/hip_runtime.h>
#include <hip/hip_bf16.h>
#include <hip/hip_fp16.h>
#include <math.h>

#define D   256
#define SE  512
#define SC  512
#define CKS 8
#define NC  64   // SC / CKS
#define KC  3

typedef __attribute__((ext_vector_type(8))) short short8_t;
typedef __attribute__((ext_vector_type(4))) float f32x4;
typedef _Float16 h2_t __attribute__((ext_vector_type(2)));
typedef _Float16 h8_t __attribute__((ext_vector_type(8)));

__device__ __forceinline__ float sigmoidf_(float x) { return 1.f / (1.f + __expf(-x)); }
__device__ __forceinline__ short bf16s(float f) {
    union { __hip_bfloat16 h; short s; } u; u.h = __float2bfloat16(f); return u.s;
}
__device__ __forceinline__ float bflo(unsigned int u) {
    union { unsigned int u; float f; } v; v.u = u << 16; return v.f;
}
__device__ __forceinline__ short h16s(float f) {
    union { _Float16 h; short s; } u; u.h = (_Float16)f; return u.s;
}
__device__ __forceinline__ float h16f(short s) {
    union { short s; _Float16 h; } u; u.s = s; return (float)u.h;
}
__device__ __forceinline__ h2_t h2u(unsigned int u) {
    union { unsigned int u; h2_t h; } v; v.u = u; return v.h;
}
__device__ __forceinline__ unsigned int u2h(h2_t h) {
    union { unsigned int u; h2_t h; } v; v.h = h; return v.u;
}
__device__ __forceinline__ float hdot2(h2_t a, h2_t b, float c) {
#if __has_builtin(__builtin_amdgcn_fdot2)
    return __builtin_amdgcn_fdot2(a, b, c, false);
#else
    h2_t p = a * b;
    return c + (float)p[0] + (float)p[1];
#endif
}
#define GLOAD_LDS16(g, l) \
    __builtin_amdgcn_global_load_lds((const __attribute__((address_space(1))) void*)(g), \
                                     (__attribute__((address_space(3))) void*)(l), 16, 0, 0)

// ============ prep: all weight conversions ============
__global__ __launch_bounds__(256) void prep_all_kernel(
    const float* __restrict__ W3, const float* __restrict__ Wih,
    const float* __restrict__ Whh, const float* __restrict__ WW,
    const float* __restrict__ repW, const float* __restrict__ clsW,
    short* __restrict__ Bprep, uint2* __restrict__ Wih16, uint2* __restrict__ Whh16,
    float4* __restrict__ WWq, float4* __restrict__ W3q,
    float4* __restrict__ repWq, unsigned int* __restrict__ clsP)
{
    const int b = blockIdx.x, t = threadIdx.x;
    if (b < 32) {
        const int idx = b * 256 + t;
        const int p = idx >> 11, k = (idx >> 3) & 255, G = idx & 7;
        const int dbase = p * 64 + ((G ^ (k & 7)) << 3);
        #pragma unroll
        for (int e = 0; e < 8; ++e)
            Bprep[idx * 8 + e] = h16s(W3[(size_t)(513 + dbase + e) * D + k]);   // fp16
    } else if (b < 416) {
        const bool ih = (b < 224);
        const int tid = (b - (ih ? 32 : 224)) * 256 + t;
        const float* W = ih ? Wih : Whh;
        const int base = (tid / 768) * 4 * 768 + (tid % 768);
        float f0 = W[base], f1 = W[base + 768], f2 = W[base + 1536], f3 = W[base + 2304];
        __half2 plo = __halves2half2(__float2half_rn(f0), __float2half_rn(f1));
        __half2 phi = __halves2half2(__float2half_rn(f2), __float2half_rn(f3));
        uint2 o; o.x = *(unsigned int*)&plo; o.y = *(unsigned int*)&phi;
        (ih ? Wih16 : Whh16)[tid] = o;
    } else if (b < 672) {
        const bool ww = (b < 544);
        const int tid = (b - (ww ? 416 : 544)) * 256 + t;
        const int h = tid >> 14, rem = tid & 16383, d4 = rem >> 8, k = rem & 255;
        const float* src = (ww ? WW : W3) + (size_t)(h * 256 + 4 * d4) * D + k;
        (ww ? WWq : W3q)[tid] = make_float4(src[0], src[256], src[512], src[768]);
    } else if (b < 736) {
        const int tid = (b - 672) * 256 + t;
        const int d4 = tid >> 8, k = tid & 255;
        const float* src = repW + (size_t)(4 * d4) * D + k;
        repWq[tid] = make_float4(src[0], src[256], src[512], src[768]);
    } else {
        unsigned int c0 = (unsigned int)(unsigned short)bf16s(clsW[t * 2]);
        unsigned int c1 = (unsigned int)(unsigned short)bf16s(clsW[t * 2 + 1]);
        clsP[t] = c0 | (c1 << 16);
    }
}

// ============ rep4: 4 rows/block (f32 + f16 outputs) + fused sq-sums ============
__global__ __launch_bounds__(256) void rep4_kernel(
    const float* __restrict__ te, const float* __restrict__ tc,
    const float4* __restrict__ repWq, const float* __restrict__ b,
    float* __restrict__ emo, float* __restrict__ cau,
    short* __restrict__ emoH, short* __restrict__ cauH,
    float* __restrict__ se2, float* __restrict__ sc2)
{
    const int r0 = blockIdx.x * 4, t = threadIdx.x;
    const float* X = (r0 < SE) ? (te + (size_t)r0 * D) : (tc + (size_t)(r0 - SE) * D);
    __shared__ __align__(16) float xs[4][D];
    #pragma unroll
    for (int r = 0; r < 4; ++r) xs[r][t] = X[r * D + t];
    __syncthreads();
    float acc0 = 0.f, acc1 = 0.f, acc2 = 0.f, acc3 = 0.f;
    #pragma unroll 8
    for (int q = 0; q < 64; ++q) {
        float4 w = repWq[q * 256 + t];
        float4 x0 = *(const float4*)&xs[0][q * 4];
        float4 x1 = *(const float4*)&xs[1][q * 4];
        float4 x2 = *(const float4*)&xs[2][q * 4];
        float4 x3 = *(const float4*)&xs[3][q * 4];
        acc0 = fmaf(x0.x, w.x, acc0); acc0 = fmaf(x0.y, w.y, acc0); acc0 = fmaf(x0.z, w.z, acc0); acc0 = fmaf(x0.w, w.w, acc0);
        acc1 = fmaf(x1.x, w.x, acc1); acc1 = fmaf(x1.y, w.y, acc1); acc1 = fmaf(x1.z, w.z, acc1); acc1 = fmaf(x1.w, w.w, acc1);
        acc2 = fmaf(x2.x, w.x, acc2); acc2 = fmaf(x2.y, w.y, acc2); acc2 = fmaf(x2.z, w.z, acc2); acc2 = fmaf(x2.w, w.w, acc2);
        acc3 = fmaf(x3.x, w.x, acc3); acc3 = fmaf(x3.y, w.y, acc3); acc3 = fmaf(x3.w, w.w, acc3); acc3 = fmaf(x3.z, w.z, acc3);
    }
    const float bb = b[t];
    float v[4] = {fmaxf(acc0 + bb, 0.f), fmaxf(acc1 + bb, 0.f), fmaxf(acc2 + bb, 0.f), fmaxf(acc3 + bb, 0.f)};
    short hv[4];
    #pragma unroll
    for (int r = 0; r < 4; ++r) hv[r] = h16s(v[r]);
    #pragma unroll
    for (int r = 0; r < 4; ++r) {
        const int row = r0 + r;
        if (row < SE) { emo[(size_t)row * D + t] = v[r]; emoH[(size_t)row * D + t] = hv[r]; }
        else { cau[(size_t)(row - SE) * D + t] = v[r]; cauH[(size_t)(row - SE) * D + t] = hv[r]; }
    }
    // fused row sum-of-squares on the f16-rounded values
    __shared__ float rsum[4][4];
    #pragma unroll
    for (int r = 0; r < 4; ++r) {
        const float f = h16f(hv[r]);
        float s = f * f;
        s += __shfl_xor(s, 1);  s += __shfl_xor(s, 2);
        s += __shfl_xor(s, 4);  s += __shfl_xor(s, 8);
        s += __shfl_xor(s, 16); s += __shfl_xor(s, 32);
        if ((t & 63) == 0) rsum[r][t >> 6] = s;
    }
    __syncthreads();
    if (t < 4) {
        const float tot = rsum[t][0] + rsum[t][1] + rsum[t][2] + rsum[t][3];
        const int row = r0 + t;
        if (row < SE) se2[row] = tot; else sc2[row - SE] = tot;
    }
}

// ============ GX = cau @ Wih + bih, 2 rows/block ============
__global__ __launch_bounds__(768) void gx2_kernel(
    const float* __restrict__ cau, const uint2* __restrict__ Wih16,
    const float* __restrict__ bih, __half* __restrict__ GX16)
{
    const int r0 = blockIdx.x * 2, t = threadIdx.x;
    __shared__ uint2 xs4[2][64];
    if (t < 128) {
        const int r = t >> 6, c = t & 63;
        float4 v = *(const float4*)&cau[(size_t)(r0 + r) * D + c * 4];
        __half2 plo = __halves2half2(__float2half_rn(v.x), __float2half_rn(v.y));
        __half2 phi = __halves2half2(__float2half_rn(v.z), __float2half_rn(v.w));
        uint2 o; o.x = *(unsigned int*)&plo; o.y = *(unsigned int*)&phi;
        xs4[r][c] = o;
    }
    __syncthreads();
    __half2 a00 = __float2half2_rn(0.f), a01 = __float2half2_rn(0.f);
    __half2 a10 = __float2half2_rn(0.f), a11 = __float2half2_rn(0.f);
    #pragma unroll 8
    for (int q = 0; q < 64; ++q) {
        uint2 w = Wih16[q * 768 + t];
        uint2 x0 = xs4[0][q], x1 = xs4[1][q];
        a00 = __hfma2(*(__half2*)&w.x, *(__half2*)&x0.x, a00);
        a01 = __hfma2(*(__half2*)&w.y, *(__half2*)&x0.y, a01);
        a10 = __hfma2(*(__half2*)&w.x, *(__half2*)&x1.x, a10);
        a11 = __hfma2(*(__half2*)&w.y, *(__half2*)&x1.y, a11);
    }
    const float bi = bih[t];
    float g0 = bi + __low2float(a00) + __high2float(a00) + __low2float(a01) + __high2float(a01);
    float g1 = bi + __low2float(a10) + __high2float(a10) + __low2float(a11) + __high2float(a11);
    GX16[(size_t)r0 * 768 + t] = __float2half_rn(g0);
    GX16[(size_t)(r0 + 1) * 768 + t] = __float2half_rn(g1);
}

// ============ GRU recurrence, Whh register-resident ============
__global__ __launch_bounds__(768) void gru_rec_kernel(
    const __half* __restrict__ GX16, const uint2* __restrict__ Whh16,
    const float* __restrict__ bhh, float* __restrict__ ch_last)
{
    const int c = blockIdx.x, t = threadIdx.x;
    __shared__ uint2 hqu[64];
    __shared__ float gh_s[768];
    uint2 wreg[64];
    #pragma unroll
    for (int q = 0; q < 64; ++q) wreg[q] = Whh16[q * 768 + t];
    float h = 0.f;
    if (t < 64) { uint2 z; z.x = 0u; z.y = 0u; hqu[t] = z; }
    __syncthreads();
    const float bh = bhh[t];
    for (int s = 0; s < CKS; ++s) {
        const int row = c * CKS + s;
        __half2 a0 = __float2half2_rn(0.f), a1 = __float2half2_rn(0.f);
        #pragma unroll
        for (int q = 0; q < 64; ++q) {
            uint2 hv = hqu[q];
            a0 = __hfma2(*(__half2*)&wreg[q].x, *(__half2*)&hv.x, a0);
            a1 = __hfma2(*(__half2*)&wreg[q].y, *(__half2*)&hv.y, a1);
        }
        gh_s[t] = bh + __low2float(a0) + __high2float(a0) + __low2float(a1) + __high2float(a1);
        __syncthreads();
        if (t < 256) {
            const float gxr = __half2float(GX16[(size_t)row * 768 + t]);
            const float gxz = __half2float(GX16[(size_t)row * 768 + 256 + t]);
            const float gxn = __half2float(GX16[(size_t)row * 768 + 512 + t]);
            float r = sigmoidf_(gxr + gh_s[t]);
            float z = sigmoidf_(gxz + gh_s[256 + t]);
            float n = tanhf(gxn + r * gh_s[512 + t]);
            h = (1.f - z) * n + z * h;
            float f1 = __shfl_down(h, 1);
            float f2 = __shfl_down(h, 2);
            float f3 = __shfl_down(h, 3);
            if ((t & 3) == 0) {
                __half2 plo = __halves2half2(__float2half_rn(h),  __float2half_rn(f1));
                __half2 phi = __halves2half2(__float2half_rn(f2), __float2half_rn(f3));
                uint2 o; o.x = *(unsigned int*)&plo; o.y = *(unsigned int*)&phi;
                hqu[t >> 2] = o;
            }
        }
        __syncthreads();
    }
    if (t < 256) ch_last[c * D + t] = h;
}

// ============ merged linears, 4 rows/block ============
__global__ __launch_bounds__(256) void dual_all4_kernel(
    const float* __restrict__ emo, const float* __restrict__ cau, const float* __restrict__ chl,
    const float4* __restrict__ WWq, const float4* __restrict__ W3q,
    const float* __restrict__ Wb, const float* __restrict__ W3b,
    float* __restrict__ HE, float* __restrict__ HC, float* __restrict__ Ae,
    short* __restrict__ AcB)
{
    const int r0 = blockIdx.x * 4, t = threadIdx.x;
    const float* X; const float4* Wq; float bias;
    int seg;
    if (r0 < 512)       { X = emo + (size_t)r0 * D;          Wq = WWq;         bias = 0.f;    seg = 0; }
    else if (r0 < 576)  { X = chl + (size_t)(r0 - 512) * D;  Wq = WWq + 16384; bias = Wb[t];  seg = 1; }
    else if (r0 < 1088) { X = emo + (size_t)(r0 - 576) * D;  Wq = W3q;         bias = 0.f;    seg = 2; }
    else                { X = cau + (size_t)(r0 - 1088) * D; Wq = W3q + 16384; bias = W3b[t]; seg = 3; }
    __shared__ __align__(16) float xs[4][D];
    #pragma unroll
    for (int r = 0; r < 4; ++r) xs[r][t] = X[r * D + t];
    __syncthreads();
    float a0 = bias, a1 = bias, a2 = bias, a3 = bias;
    #pragma unroll 8
    for (int q = 0; q < 64; ++q) {
        float4 w = Wq[q * 256 + t];
        float4 x0 = *(const float4*)&xs[0][q * 4];
        float4 x1 = *(const float4*)&xs[1][q * 4];
        float4 x2 = *(const float4*)&xs[2][q * 4];
        float4 x3 = *(const float4*)&xs[3][q * 4];
        a0 = fmaf(x0.x, w.x, a0); a0 = fmaf(x0.y, w.y, a0); a0 = fmaf(x0.z, w.z, a0); a0 = fmaf(x0.w, w.w, a0);
        a1 = fmaf(x1.x, w.x, a1); a1 = fmaf(x1.y, w.y, a1); a1 = fmaf(x1.z, w.z, a1); a1 = fmaf(x1.w, w.w, a1);
        a2 = fmaf(x2.x, w.x, a2); a2 = fmaf(x2.y, w.y, a2); a2 = fmaf(x2.z, w.z, a2); a2 = fmaf(x2.w, w.w, a2);
        a3 = fmaf(x3.x, w.x, a3); a3 = fmaf(x3.y, w.y, a3); a3 = fmaf(x3.z, w.z, a3); a3 = fmaf(x3.w, w.w, a3);
    }
    float av[4] = {a0, a1, a2, a3};
    #pragma unroll
    for (int r = 0; r < 4; ++r) {
        const int row = r0 + r;
        if (seg == 0)      HE[(size_t)row * D + t] = av[r];
        else if (seg == 1) HC[(size_t)(row - 512) * D + t] = av[r];
        else if (seg == 2) Ae[(size_t)(row - 576) * D + t] = av[r];
        else               AcB[(size_t)(row - 1088) * D + t] = bf16s(av[r]);
    }
}

// ============ phase2 ============
__global__ __launch_bounds__(256) void phase2_kernel(
    const float* __restrict__ HE, const float* __restrict__ HC,
    const float* __restrict__ WoW, const float* __restrict__ Wob,
    float* __restrict__ out)
{
    const int i = blockIdx.x, t = threadIdx.x;
    const int c = t >> 2, sub = t & 3;
    __shared__ __align__(16) float he_s[D];
    he_s[t] = HE[(size_t)i * D + t];
    __syncthreads();
    float v0 = 0.f, v1 = 0.f;
    const float* hcRow = HC + (size_t)c * D;
    #pragma unroll 4
    for (int kk = 0; kk < 16; ++kk) {
        const int k4 = sub * 64 + kk * 4;
        float4 he = *(const float4*)&he_s[k4];
        float4 hc = *(const float4*)&hcRow[k4];
        float hk;
        hk = sigmoidf_(he.x + hc.x); { float2 wo = *(const float2*)&WoW[(k4 + 0) * 2]; v0 = fmaf(hk, wo.x, v0); v1 = fmaf(hk, wo.y, v1); }
        hk = sigmoidf_(he.y + hc.y); { float2 wo = *(const float2*)&WoW[(k4 + 1) * 2]; v0 = fmaf(hk, wo.x, v0); v1 = fmaf(hk, wo.y, v1); }
        hk = sigmoidf_(he.z + hc.z); { float2 wo = *(const float2*)&WoW[(k4 + 2) * 2]; v0 = fmaf(hk, wo.x, v0); v1 = fmaf(hk, wo.y, v1); }
        hk = sigmoidf_(he.w + hc.w); { float2 wo = *(const float2*)&WoW[(k4 + 3) * 2]; v0 = fmaf(hk, wo.x, v0); v1 = fmaf(hk, wo.y, v1); }
    }
    v0 += __shfl_xor(v0, 1); v0 += __shfl_xor(v0, 2);
    v1 += __shfl_xor(v1, 1); v1 += __shfl_xor(v1, 2);
    if (sub == 0) {
        float l0 = v0 + Wob[0], l1 = v1 + Wob[1];
        float m = fmaxf(l0, l1);
        float lse = m + __logf(__expf(l0 - m) + __expf(l1 - m));
        float2 o; o.x = l0 - lse; o.y = l1 - lse;
        *(float2*)&out[((size_t)i * NC + c) * 2] = o;
    }
}

// ============ p v17 (proven 84us): fp16 packed A-build + f16 MFMA ============
// grid (64 i-chunks, 8 jt x 2 kh); 8 waves = 4wj x 2wk; wave 16j x 64k
__global__ __launch_bounds__(512) void p_kernel(
    const short* __restrict__ emoH, const float* __restrict__ se2, const float* __restrict__ sc2,
    const float* __restrict__ Ae,  const short* __restrict__ AcB,
    const float* __restrict__ wn,  const short* __restrict__ Bprep,
    const short* __restrict__ cauH, const float* __restrict__ clsW,
    float* __restrict__ pp)   // partial [kh<2][i][j][2]
{
    const int t = threadIdx.x;
    const int i0 = blockIdx.x * 8;
    const int jt = blockIdx.y >> 1, kh = blockIdx.y & 1;
    const int j0 = jt * 64;
    const int l = t & 63, wave = t >> 6;
    const int hi = l >> 4, lo = l & 15;
    const int wj = wave >> 1, wk = wave & 1;
    const int j_base = wj * 16, k_base = wk * 64;   // k_base LOCAL (0..127)
    const int myj = j0 + j_base + lo;

    __shared__ __align__(16) short B_s[32768];   // 64 KB: [p<4][klocal<128][G<8][e<8] (f16)
    __shared__ float part2[64][2][2];

    // stage this k-half of B (linear dest, pre-swizzled source)
    #pragma unroll
    for (int r = 0; r < 8; ++r) {
        const int g = r * 512 + t;
        const int p = g >> 10, rem = g & 1023;
        GLOAD_LDS16(Bprep + ((size_t)(p * 256 + kh * 128) * 8 + rem) * 8, &B_s[g * 8]);
    }

    int kcol[4]; float wn_r[4], c0_r[4], c1_r[4];
    #pragma unroll
    for (int kf = 0; kf < 4; ++kf) {
        const int kg = kh * 128 + k_base + kf * 16 + lo;
        kcol[kf] = kg;
        wn_r[kf] = wn[kg];
        c0_r[kf] = clsW[kg * 2]; c1_r[kf] = clsW[kg * 2 + 1];
    }
    const int swzf0 = (hi ^ (lo & 7)) << 3;
    const int swzf1 = ((4 + hi) ^ (lo & 7)) << 3;
    const float sc2_l = sc2[myj];
    float Ac_r[4][4];
    #pragma unroll
    for (int q = 0; q < 4; ++q)
        #pragma unroll
        for (int kf = 0; kf < 4; ++kf)
            Ac_r[q][kf] = bflo((unsigned int)(unsigned short)AcB[(size_t)(j0 + j_base + hi * 4 + q) * D + kcol[kf]]);

    // this lane's 8 raw cau f16 frags (row myj) -> 32 VGPR, i-invariant
    uint4 cfr[8];
    #pragma unroll
    for (int s = 0; s < 8; ++s) {
        const int p = s >> 1, df = s & 1;
        cfr[s] = *(const uint4*)&cauH[(size_t)myj * D + p * 64 + (df * 4 + hi) * 8];
    }
    __syncthreads();   // B resident

    #pragma unroll 1
    for (int ii = 0; ii < 8; ++ii) {
        const int i = i0 + ii;
        __syncthreads();   // LICM fence for B_s reads + part2 reuse guard
        f32x4 acc[4];
        #pragma unroll
        for (int kf = 0; kf < 4; ++kf) acc[kf] = (f32x4)(0.f);
        float dot = 0.f;

        #pragma unroll
        for (int s = 0; s < 8; ++s) {
            const int p = s >> 1, df = s & 1;
            const uint4 eu = *(const uint4*)&emoH[(size_t)i * D + p * 64 + (df * 4 + hi) * 8];
            const uint4 cu = cfr[s];
            const h2_t e0 = h2u(eu.x), e1 = h2u(eu.y), e2 = h2u(eu.z), e3 = h2u(eu.w);
            const h2_t c0 = h2u(cu.x), c1 = h2u(cu.y), c2 = h2u(cu.z), c3 = h2u(cu.w);
            dot = hdot2(e0, c0, dot);
            dot = hdot2(e1, c1, dot);
            dot = hdot2(e2, c2, dot);
            dot = hdot2(e3, c3, dot);
            union { uint4 u; h8_t h; } afu;
            afu.u.x = u2h(e0 * c0);
            afu.u.y = u2h(e1 * c1);
            afu.u.z = u2h(e2 * c2);
            afu.u.w = u2h(e3 * c3);
            const int swz = df ? swzf1 : swzf0;
            #pragma unroll
            for (int kf = 0; kf < 4; ++kf) {
                const h8_t bf = *(const h8_t*)&B_s[p * 8192 + (k_base + kf * 16 + lo) * 64 + swz];
                acc[kf] = __builtin_amdgcn_mfma_f32_16x16x32_f16(afu.h, bf, acc[kf], 0, 0, 0);
            }
        }

        // it2 via dot identity (sum over hi groups)
        float dv = dot;
        dv += __shfl_xor(dv, 16); dv += __shfl_xor(dv, 32);
        const float itv_own = sqrtf(fmaxf(se2[i] + sc2_l - 2.f * dv, 0.f));   // for row lo

        // epilogue: partial cls-dot over this wave's 64 k
        float Ae_r[4];
        #pragma unroll
        for (int kf = 0; kf < 4; ++kf) Ae_r[kf] = Ae[(size_t)i * D + kcol[kf]];
        #pragma unroll
        for (int q = 0; q < 4; ++q) {
            const int j = j_base + hi * 4 + q;
            const float itv = __shfl(itv_own, hi * 4 + q);
            float sv0 = 0.f, sv1 = 0.f;
            #pragma unroll
            for (int kf = 0; kf < 4; ++kf) {
                float s = acc[kf][q] + Ae_r[kf] + Ac_r[q][kf] + itv * wn_r[kf];
                float h = fmaxf(s, 0.f);
                sv0 = fmaf(h, c0_r[kf], sv0); sv1 = fmaf(h, c1_r[kf], sv1);
            }
            sv0 += __shfl_xor(sv0, 1); sv0 += __shfl_xor(sv0, 2);
            sv0 += __shfl_xor(sv0, 4); sv0 += __shfl_xor(sv0, 8);
            sv1 += __shfl_xor(sv1, 1); sv1 += __shfl_xor(sv1, 2);
            sv1 += __shfl_xor(sv1, 4); sv1 += __shfl_xor(sv1, 8);
            if (lo == 0) { part2[j][wk][0] = sv0; part2[j][wk][1] = sv1; }
        }
        __syncthreads();   // part2 ready
        if (t < 64) {
            float2 o;
            o.x = part2[t][0][0] + part2[t][1][0];
            o.y = part2[t][0][1] + part2[t][1][1];
            *(float2*)&pp[(((size_t)kh * SE + i) * SC + j0 + t) * 2] = o;
        }
    }
}

// ============ pfin + L_cau merged: one block per i ============
__global__ __launch_bounds__(512) void pfin_lcau_kernel(
    const float* __restrict__ pp, const float* __restrict__ clsb,
    const int* __restrict__ label3,
    float* __restrict__ pout, float* __restrict__ L)
{
    const int i = blockIdx.x, j = threadIdx.x;
    const float2 a = *(const float2*)&pp[((size_t)i * SC + j) * 2];
    const float2 b = *(const float2*)&pp[(((size_t)SE + i) * SC + j) * 2];
    float s0 = a.x + b.x + clsb[0];
    float s1 = a.y + b.y + clsb[1];
    float m = fmaxf(s0, s1);
    float lse = m + __logf(__expf(s0 - m) + __expf(s1 - m));
    float2 o; o.x = s0 - lse; o.y = s1 - lse;
    *(float2*)&pout[((size_t)i * SC + j) * 2] = o;
    // L_cau: zero the row, then scatter
    if (j < 128) {
        float4 z; z.x = z.y = z.z = z.w = 0.f;
        *(float4*)&L[(size_t)i * SC + j * 4] = z;
    }
    __syncthreads();
    if (j < KC) {
        int idx = label3[i * KC + j];
        L[(size_t)i * SC + idx] = 1.0f;
    }
}

extern "C" void kernel_launch(void* const* d_in, const int* in_sizes, int n_in,
                              void* d_out, int out_size, void* d_ws, size_t ws_size,
                              hipStream_t stream)
{
    const float* text_emo = (const float*)d_in[0];
    const float* text_cau = (const float*)d_in[1];
    const int*   label3   = (const int*)d_in[3];
    const float* rep_W = (const float*)d_in[5];
    const float* rep_b = (const float*)d_in[6];
    const float* W_W   = (const float*)d_in[7];
    const float* W_b   = (const float*)d_in[8];
    const float* Wo_W  = (const float*)d_in[9];
    const float* Wo_b  = (const float*)d_in[10];
    const float* gWih  = (const float*)d_in[11];
    const float* gWhh  = (const float*)d_in[12];
    const float* gbih  = (const float*)d_in[13];
    const float* gbhh  = (const float*)d_in[14];
    const float* W3_W  = (const float*)d_in[15];
    const float* W3_b  = (const float*)d_in[16];
    const float* cls_W = (const float*)d_in[17];
    const float* cls_b = (const float*)d_in[18];

    float* out        = (float*)d_out;
    float* phase2_out = out;
    float* p_out      = out + SE * NC * 2;
    float* lcau_out   = out + SE * NC * 2 + SE * SC * 2;

    // workspace layout (floats): ~9.5 MB total
    float* ws  = (float*)d_ws;
    float* emo = ws;                           // 131072
    float* cau = emo + 131072;                 // 131072
    float* chl = cau + 131072;                 // 16384
    float* HE  = chl + 16384;                  // 131072
    float* HC  = HE + 131072;                  // 16384
    float* Ae  = HC + 16384;                   // 131072
    float4* WWq = (float4*)(Ae + 131072);      // 32768 f4
    float4* W3q = WWq + 32768;                 // 32768 f4
    short* AcB   = (short*)(W3q + 32768);      // 131072 bf16
    short* Bprep = AcB + 131072;               // 65536 (f16)
    uint2* Wih16 = (uint2*)(Bprep + 65536);    // 49152 u2
    uint2* Whh16 = Wih16 + 49152;              // 49152 u2
    float4* repWq = (float4*)(Whh16 + 49152);  // 16384 f4
    short* cauH = (short*)(repWq + 16384);     // 131072 f16
    short* emoH = cauH + 131072;               // 131072 f16
    unsigned int* clsP = (unsigned int*)(emoH + 131072);  // 256
    float* pp = (float*)(clsP + 256);          // 1048576 f: [2][512][512][2]
    float* sc2 = pp + 1048576;                 // 512
    float* se2 = sc2 + 512;                    // 512
    __half* GX16 = (__half*)HE;                // overlays HE/HC/Ae

    prep_all_kernel<<<737, 256, 0, stream>>>(W3_W, gWih, gWhh, W_W, rep_W, cls_W,
                                             Bprep, Wih16, Whh16, WWq, W3q, repWq, clsP);
    rep4_kernel<<<256, 256, 0, stream>>>(text_emo, text_cau, repWq, rep_b, emo, cau,
                                         emoH, cauH, se2, sc2);
    gx2_kernel<<<256, 768, 0, stream>>>(cau, Wih16, gbih, GX16);
    gru_rec_kernel<<<NC, 768, 0, stream>>>(GX16, Whh16, gbhh, chl);
    dual_all4_kernel<<<400, 256, 0, stream>>>(emo, cau, chl, WWq, W3q, W_b, W3_b,
                                              HE, HC, Ae, AcB);
    phase2_kernel<<<SE, 256, 0, stream>>>(HE, HC, Wo_W, Wo_b, phase2_out);
    p_kernel<<<dim3(64, 16), 512, 0, stream>>>(emoH, se2, sc2, Ae, AcB, W3_W + 512 * D,
                                               Bprep, cauH, cls_W, pp);
    pfin_lcau_kernel<<<SE, 512, 0, stream>>>(pp, cls_b, label3, p_out, lcau_out);
}